// Round 1
// baseline (63.426 us; speedup 1.0000x reference)
//
#include <hip/hip_runtime.h>
#include <math.h>

#define TAB_DIM 6
#define C64 64
#define HID 32
#define BB 2
#define SZ 64
#define BC (BB * C64)          // 128
#define NOUT (33554432)        // B*C*X*Y*Z
#define EPSF 1.1920929e-07f

// ---------------------------------------------------------------------------
// Kernel 1: tiny MLP + gaussian tables + l2 scalar. One block, 256 threads.
// ---------------------------------------------------------------------------
__global__ void setup_kernel(const float* __restrict__ tab,
                             const float* __restrict__ w1, const float* __restrict__ b1,
                             const float* __restrict__ w2, const float* __restrict__ b2,
                             const float* __restrict__ wp, const float* __restrict__ bp,
                             const float* __restrict__ wsg, const float* __restrict__ bsg,
                             float* __restrict__ pre,    // [128] = 1-scale
                             float* __restrict__ shiftv, // [128]
                             float* __restrict__ gx,     // [128*64]
                             float* __restrict__ gy,     // [128*64]
                             float* __restrict__ gz,     // [128*64]
                             float* __restrict__ l2_out)
{
    __shared__ float emb1[BB][HID];
    __shared__ float emb2[BB][HID];
    __shared__ float p[BB][5 * C64];   // 2 x 320
    __shared__ float s[BB][3 * C64];   // 2 x 192
    __shared__ float mu[3][BC], sg[3][BC];
    __shared__ float l2acc[5][BC];

    const int tid = threadIdx.x;

    // layer 1: emb1 = tanh(tab @ w1.T + b1)
    if (tid < BB * HID) {
        int b = tid >> 5, j = tid & 31;
        float acc = b1[j];
        #pragma unroll
        for (int k = 0; k < TAB_DIM; ++k) acc += tab[b * TAB_DIM + k] * w1[j * TAB_DIM + k];
        emb1[b][j] = tanhf(acc);
    }
    __syncthreads();

    // layer 2: emb2 = tanh(emb1 @ w2.T + b2)
    if (tid < BB * HID) {
        int b = tid >> 5, j = tid & 31;
        float acc = b2[j];
        #pragma unroll
        for (int k = 0; k < HID; ++k) acc += emb1[b][k] * w2[j * HID + k];
        emb2[b][j] = tanhf(acc);
    }
    __syncthreads();

    // heads: p (2x320), s (2x192) -> 1024 outputs, 4 per thread
    for (int t = tid; t < BB * 5 * C64 + BB * 3 * C64; t += 256) {
        if (t < BB * 5 * C64) {
            int b = t / (5 * C64), j = t % (5 * C64);
            float acc = bp[j];
            #pragma unroll
            for (int k = 0; k < HID; ++k) acc += emb2[b][k] * wp[j * HID + k];
            p[b][j] = acc;
        } else {
            int u = t - BB * 5 * C64;
            int b = u / (3 * C64), j = u % (3 * C64);
            float acc = bsg[j];
            #pragma unroll
            for (int k = 0; k < HID; ++k) acc += emb2[b][k] * wsg[j * HID + k];
            s[b][j] = 1.0f / (1.0f + expf(-acc));
        }
    }
    __syncthreads();

    // per-(b,c) derived params
    if (tid < BC) {
        int b = tid >> 6, c = tid & 63;
        float sc  = p[b][c];
        float sh  = p[b][C64 + c];
        float ma  = tanhf(p[b][2 * C64 + c]);
        float mb  = tanhf(p[b][3 * C64 + c]);
        float mc  = tanhf(p[b][4 * C64 + c]);
        float sa  = s[b][c];
        float sb  = s[b][C64 + c];
        float scc = s[b][2 * C64 + c];
        pre[tid]    = 1.0f - sc;
        shiftv[tid] = sh;
        mu[0][tid] = ma; mu[1][tid] = mb; mu[2][tid] = mc;
        sg[0][tid] = sa; sg[1][tid] = sb; sg[2][tid] = scc;
        l2acc[0][tid] = sc * sc;
        l2acc[1][tid] = sh * sh;
        l2acc[2][tid] = sa * sa;
        l2acc[3][tid] = sb * sb;
        l2acc[4][tid] = scc * scc;
    }
    __syncthreads();

    if (tid == 0) {
        float tot = 0.0f;
        for (int q = 0; q < 5; ++q) {
            float ssum = 0.0f;
            for (int i = 0; i < BC; ++i) ssum += l2acc[q][i];
            tot += sqrtf(ssum);
        }
        *l2_out = tot;
    }

    // gaussian tables: 3 * 128 * 64 entries
    for (int idx = tid; idx < 3 * BC * SZ; idx += 256) {
        int tb = idx / (BC * SZ);
        int r  = idx % (BC * SZ);
        int bc = r >> 6, i = r & 63;
        float m   = mu[tb][bc] * (SZ * 0.5f) + (SZ * 0.5f) - 0.5f;  // mu*32 + 31.5
        float sgm = sg[tb][bc] * 3.5f + EPSF;
        float d   = ((float)i - m) / sgm;
        float g   = expf(-0.5f * d * d);
        float* dst = (tb == 0) ? gx : (tb == 1) ? gy : gz;
        dst[r] = g;
    }
}

// ---------------------------------------------------------------------------
// Kernel 2: out = pre[bc]*gx[bc,x] * x * gy[bc,y]*gz[bc,z] + shift[bc]
// One block per (b,c,x) plane of 64x64 = 4096 elems. float4 everywhere.
// ---------------------------------------------------------------------------
__global__ void __launch_bounds__(256) apply_kernel(
        const float* __restrict__ xin,
        const float* __restrict__ pre, const float* __restrict__ shiftv,
        const float* __restrict__ gx, const float* __restrict__ gy,
        const float* __restrict__ gz,
        float* __restrict__ out)
{
    __shared__ float gys[SZ], gzs[SZ];
    const int blk = blockIdx.x;        // b*C*X + c*X + x
    const int bc  = blk >> 6;
    const int xi  = blk & 63;
    const int tid = threadIdx.x;

    if (tid < SZ)            gys[tid]      = gy[bc * SZ + tid];
    else if (tid < 2 * SZ)   gzs[tid - SZ] = gz[bc * SZ + tid - SZ];

    const float pv = pre[bc] * gx[bc * SZ + xi];
    const float sh = shiftv[bc];
    __syncthreads();

    const float4* x4 = (const float4*)(xin + (size_t)blk * (SZ * SZ));
    float4*       o4 = (float4*)(out + (size_t)blk * (SZ * SZ));

    #pragma unroll
    for (int k = 0; k < 4; ++k) {
        int i4 = tid + k * 256;        // 0..1023 float4s in this plane
        int y  = i4 >> 4;              // 16 float4 per row of 64
        int z0 = (i4 & 15) << 2;
        float4 xv = x4[i4];
        float  m  = pv * gys[y];
        float4 ov;
        ov.x = fmaf(m * gzs[z0 + 0], xv.x, sh);
        ov.y = fmaf(m * gzs[z0 + 1], xv.y, sh);
        ov.z = fmaf(m * gzs[z0 + 2], xv.z, sh);
        ov.w = fmaf(m * gzs[z0 + 3], xv.w, sh);
        o4[i4] = ov;
    }
}

// ---------------------------------------------------------------------------
extern "C" void kernel_launch(void* const* d_in, const int* in_sizes, int n_in,
                              void* d_out, int out_size, void* d_ws, size_t ws_size,
                              hipStream_t stream)
{
    const float* x   = (const float*)d_in[0];
    const float* tab = (const float*)d_in[1];
    const float* w1  = (const float*)d_in[2];
    const float* b1  = (const float*)d_in[3];
    const float* w2  = (const float*)d_in[4];
    const float* b2  = (const float*)d_in[5];
    const float* wp  = (const float*)d_in[6];
    const float* bp  = (const float*)d_in[7];
    const float* wsg = (const float*)d_in[8];
    const float* bsg = (const float*)d_in[9];

    float* ws  = (float*)d_ws;
    float* pre = ws;               // 128
    float* shf = ws + 128;         // 128
    float* gx  = ws + 256;         // 8192
    float* gy  = gx + BC * SZ;     // 8192
    float* gz  = gy + BC * SZ;     // 8192

    float* out = (float*)d_out;
    float* l2  = out + (out_size - 1);   // last element = l2 scalar

    setup_kernel<<<1, 256, 0, stream>>>(tab, w1, b1, w2, b2, wp, bp, wsg, bsg,
                                        pre, shf, gx, gy, gz, l2);

    apply_kernel<<<BB * C64 * SZ, 256, 0, stream>>>(x, pre, shf, gx, gy, gz, out);
}

// Round 3
// 49.482 us; speedup vs baseline: 1.2818x; 1.2818x over previous
//
#include <hip/hip_runtime.h>
#include <math.h>

#define EPSF 1.1920929e-07f

typedef float f4 __attribute__((ext_vector_type(4)));

__device__ __forceinline__ float sigmoidf_(float v) { return 1.0f / (1.0f + expf(-v)); }

// ---------------------------------------------------------------------------
// Fully fused: each block owns one (b,c,x) plane of 64x64 elems.
// It redundantly recomputes the tiny MLP + its gaussian rows (L2-cached
// weights, ~2K MACs), then streams 16 KB in / 16 KB out. Block 0 also
// computes the l2 scalar.
// ---------------------------------------------------------------------------
__global__ void __launch_bounds__(256) fused_kernel(
        const float* __restrict__ xin, const float* __restrict__ tab,
        const float* __restrict__ w1,  const float* __restrict__ b1,
        const float* __restrict__ w2,  const float* __restrict__ b2,
        const float* __restrict__ wp,  const float* __restrict__ bp,
        const float* __restrict__ wsg, const float* __restrict__ bsg,
        float* __restrict__ out, int out_last)
{
    __shared__ float emb1[2][32];
    __shared__ float emb2[2][32];
    __shared__ float head[8];
    __shared__ float gys[64], gzs[64];
    __shared__ float pv_sh, sh_sh;

    const int blk = blockIdx.x;        // b*64*64 + c*64 + x
    const int bc  = blk >> 6;
    const int xi  = blk & 63;
    const int b   = bc >> 6;
    const int c   = bc & 63;
    const int tid = threadIdx.x;

    // MLP layer 1: emb1[b] = tanh(tab[b] @ w1.T + b1), both batches, 64 thr
    if (tid < 64) {
        int bb = tid >> 5, j = tid & 31;
        float acc = b1[j];
        #pragma unroll
        for (int k = 0; k < 6; ++k) acc += tab[bb * 6 + k] * w1[j * 6 + k];
        emb1[bb][j] = tanhf(acc);
    }
    __syncthreads();

    // MLP layer 2
    if (tid < 64) {
        int bb = tid >> 5, j = tid & 31;
        float acc = b2[j];
        #pragma unroll
        for (int k = 0; k < 32; ++k) acc += emb1[bb][k] * w2[j * 32 + k];
        emb2[bb][j] = tanhf(acc);
    }
    __syncthreads();

    // 8 head values for this (b,c):
    // 0:scale 1:shift 2:mu_a 3:mu_b 4:mu_c (wp rows q*64+c)
    // 5:sa 6:sb 7:sc                        (ws rows (q-5)*64+c)
    if (tid < 8) {
        const float* W  = (tid < 5) ? wp  : wsg;
        const float* Bv = (tid < 5) ? bp  : bsg;
        int row = ((tid < 5) ? tid : (tid - 5)) * 64 + c;
        float acc = Bv[row];
        #pragma unroll
        for (int k = 0; k < 32; ++k) acc += emb2[b][k] * W[row * 32 + k];
        head[tid] = acc;
    }
    __syncthreads();

    // gaussian rows + plane constants
    if (tid < 64) {
        float m  = tanhf(head[3]) * 32.0f + 31.5f;
        float sg = sigmoidf_(head[6]) * 3.5f + EPSF;
        float d  = ((float)tid - m) / sg;
        gys[tid] = expf(-0.5f * d * d);
    } else if (tid < 128) {
        int i = tid - 64;
        float m  = tanhf(head[4]) * 32.0f + 31.5f;
        float sg = sigmoidf_(head[7]) * 3.5f + EPSF;
        float d  = ((float)i - m) / sg;
        gzs[i] = expf(-0.5f * d * d);
    } else if (tid == 128) {
        float m  = tanhf(head[2]) * 32.0f + 31.5f;
        float sg = sigmoidf_(head[5]) * 3.5f + EPSF;
        float d  = ((float)xi - m) / sg;
        pv_sh = (1.0f - head[0]) * expf(-0.5f * d * d);
        sh_sh = head[1];
    }

    // block 0 only: l2 = sum of 5 frobenius norms (640 dot-32s over 256 thr)
    if (blk == 0) {
        __shared__ float sq[5][128];
        for (int t = tid; t < 640; t += 256) {
            int q = t / 128, r = t % 128;
            int bb = r >> 6, cc = r & 63;
            const float* W  = (q < 2) ? wp  : wsg;
            const float* Bv = (q < 2) ? bp  : bsg;
            int row = ((q < 2) ? q : (q - 2)) * 64 + cc;
            float acc = Bv[row];
            #pragma unroll
            for (int k = 0; k < 32; ++k) acc += emb2[bb][k] * W[row * 32 + k];
            if (q >= 2) acc = sigmoidf_(acc);
            sq[q][r] = acc * acc;
        }
        __syncthreads();
        if (tid == 0) {
            float tot = 0.0f;
            for (int q = 0; q < 5; ++q) {
                float ssum = 0.0f;
                for (int i = 0; i < 128; ++i) ssum += sq[q][i];
                tot += sqrtf(ssum);
            }
            out[out_last] = tot;
        }
    }
    __syncthreads();

    // streaming phase: out = pv*gy[y]*gz[z] * x + sh over this 64x64 plane
    const float pv = pv_sh;
    const float sh = sh_sh;
    const f4* x4 = (const f4*)(xin + (size_t)blk * 4096);
    f4*       o4 = (f4*)(out + (size_t)blk * 4096);

    #pragma unroll
    for (int k = 0; k < 4; ++k) {
        int i4 = tid + k * 256;        // 1024 float4s per plane
        int y  = i4 >> 4;
        int z0 = (i4 & 15) << 2;
        f4 xv = __builtin_nontemporal_load(&x4[i4]);
        float m = pv * gys[y];
        f4 ov;
        ov.x = fmaf(m * gzs[z0 + 0], xv.x, sh);
        ov.y = fmaf(m * gzs[z0 + 1], xv.y, sh);
        ov.z = fmaf(m * gzs[z0 + 2], xv.z, sh);
        ov.w = fmaf(m * gzs[z0 + 3], xv.w, sh);
        __builtin_nontemporal_store(ov, &o4[i4]);
    }
}

// ---------------------------------------------------------------------------
extern "C" void kernel_launch(void* const* d_in, const int* in_sizes, int n_in,
                              void* d_out, int out_size, void* d_ws, size_t ws_size,
                              hipStream_t stream)
{
    const float* x   = (const float*)d_in[0];
    const float* tab = (const float*)d_in[1];
    const float* w1  = (const float*)d_in[2];
    const float* b1  = (const float*)d_in[3];
    const float* w2  = (const float*)d_in[4];
    const float* b2  = (const float*)d_in[5];
    const float* wp  = (const float*)d_in[6];
    const float* bp  = (const float*)d_in[7];
    const float* wsg = (const float*)d_in[8];
    const float* bsg = (const float*)d_in[9];

    float* out = (float*)d_out;

    fused_kernel<<<2 * 64 * 64, 256, 0, stream>>>(
        x, tab, w1, b1, w2, b2, wp, bp, wsg, bsg, out, out_size - 1);
}